// Round 1
// baseline (927.631 us; speedup 1.0000x reference)
//
#include <hip/hip_runtime.h>

typedef unsigned short u16;
typedef unsigned int u32;

typedef __attribute__((ext_vector_type(8))) short bf16x8;
typedef __attribute__((ext_vector_type(4))) float f32x4;

__device__ __forceinline__ u16 f2bf(float f) {
  u32 u = __builtin_bit_cast(u32, f);
  u32 r = (u + 0x7fffu + ((u >> 16) & 1u)) >> 16;
  return (u16)r;
}
__device__ __forceinline__ float bf2f(u16 h) {
  return __builtin_bit_cast(float, (u32)h << 16);
}

#define GLD16(g, l)                                       \
  __builtin_amdgcn_global_load_lds(                       \
      (__attribute__((address_space(1))) void*)(g),       \
      (__attribute__((address_space(3))) void*)(l), 16, 0, 0)

// ---------------- fp32 -> bf16 convert ----------------
__global__ __launch_bounds__(256) void cvt_bf16(const float* __restrict__ src,
                                                u16* __restrict__ dst, int n4) {
  int i = blockIdx.x * 256 + threadIdx.x;
  if (i >= n4) return;
  float4 v = ((const float4*)src)[i];
  ushort4 o;
  o.x = f2bf(v.x); o.y = f2bf(v.y); o.z = f2bf(v.z); o.w = f2bf(v.w);
  ((ushort4*)dst)[i] = o;
}

// ---------------- RoPE in place on bf16 [B,T,C], full-dim pairs (c, c+1024) ----
__global__ __launch_bounds__(256) void rope_ip(u16* buf,
                                               const float* __restrict__ cosT,
                                               const float* __restrict__ sinT) {
  int i = blockIdx.x * 256 + threadIdx.x;  // < B*T*256 = 2097152
  int c4 = (i & 255) << 2;                 // 0..1020
  size_t bt = (size_t)(i >> 8);
  int t = (int)(bt & 2047);
  u16* p1 = buf + bt * 2048 + c4;
  u16* p2 = p1 + 1024;
  ushort4 x1 = *(const ushort4*)p1;
  ushort4 x2 = *(const ushort4*)p2;
  float4 c1 = *(const float4*)&cosT[(size_t)t * 2048 + c4];
  float4 s1 = *(const float4*)&sinT[(size_t)t * 2048 + c4];
  float4 c2 = *(const float4*)&cosT[(size_t)t * 2048 + c4 + 1024];
  float4 s2 = *(const float4*)&sinT[(size_t)t * 2048 + c4 + 1024];
  float a0 = bf2f(x1.x), a1 = bf2f(x1.y), a2 = bf2f(x1.z), a3 = bf2f(x1.w);
  float b0 = bf2f(x2.x), b1 = bf2f(x2.y), b2 = bf2f(x2.z), b3 = bf2f(x2.w);
  ushort4 o1, o2;
  o1.x = f2bf(a0 * c1.x - b0 * s1.x);
  o1.y = f2bf(a1 * c1.y - b1 * s1.y);
  o1.z = f2bf(a2 * c1.z - b2 * s1.z);
  o1.w = f2bf(a3 * c1.w - b3 * s1.w);
  o2.x = f2bf(b0 * c2.x + a0 * s2.x);
  o2.y = f2bf(b1 * c2.y + a1 * s2.y);
  o2.z = f2bf(b2 * c2.z + a2 * s2.z);
  o2.w = f2bf(b3 * c2.w + a3 * s2.w);
  *(ushort4*)p1 = o1;
  *(ushort4*)p2 = o2;
}

// ---------------- bf16 GEMM: D[m][n] = sum_k A[m][k]*W[n][k] + bias[n] ----------
// M=8192, N=2048, K=2048 fixed. 128x128 tile, BK=32, 4 waves (2x2 of 64x64).
// Epilogue: optional fp32 out, bf16 out, bf16 transposed-out ([b][h][d][t]).
__global__ __launch_bounds__(256) void gemm_bt(const u16* __restrict__ A,
                                               const u16* __restrict__ Wm,
                                               const float* __restrict__ bias,
                                               float* __restrict__ outF,
                                               u16* __restrict__ outB,
                                               u16* __restrict__ outT) {
  __shared__ __attribute__((aligned(16))) u16 As[128 * 32];
  __shared__ __attribute__((aligned(16))) u16 Bs[128 * 32];
  const int tid = threadIdx.x;
  const int lane = tid & 63;
  const int w = tid >> 6;
  const int wr = w >> 1, wc = w & 1;
  const int m0 = blockIdx.y * 128, n0 = blockIdx.x * 128;
  const int r15 = lane & 15, rg = lane >> 4;

  f32x4 acc[4][4] = {};

  const int srow = tid >> 2;
  const int skoff = (tid & 3) << 3;
  for (int kt = 0; kt < 2048; kt += 32) {
    __syncthreads();
    const u16* gA = A + (size_t)(m0 + srow) * 2048 + kt + skoff;
    u16* lA = As + srow * 32 + skoff;  // byte offset = tid*16
    GLD16(gA, lA);
    GLD16(gA + (size_t)64 * 2048, lA + 64 * 32);
    const u16* gB = Wm + (size_t)(n0 + srow) * 2048 + kt + skoff;
    u16* lB = Bs + srow * 32 + skoff;
    GLD16(gB, lB);
    GLD16(gB + (size_t)64 * 2048, lB + 64 * 32);
    __syncthreads();
    bf16x8 a[4], b[4];
#pragma unroll
    for (int mf = 0; mf < 4; mf++)
      a[mf] = *(const bf16x8*)&As[(wr * 64 + mf * 16 + r15) * 32 + rg * 8];
#pragma unroll
    for (int nf = 0; nf < 4; nf++)
      b[nf] = *(const bf16x8*)&Bs[(wc * 64 + nf * 16 + r15) * 32 + rg * 8];
#pragma unroll
    for (int mf = 0; mf < 4; mf++)
#pragma unroll
      for (int nf = 0; nf < 4; nf++)
        acc[mf][nf] =
            __builtin_amdgcn_mfma_f32_16x16x32_bf16(a[mf], b[nf], acc[mf][nf], 0, 0, 0);
  }
#pragma unroll
  for (int mf = 0; mf < 4; mf++)
#pragma unroll
    for (int nf = 0; nf < 4; nf++) {
      int n = n0 + wc * 64 + nf * 16 + r15;
      float bs = bias[n];
#pragma unroll
      for (int r = 0; r < 4; r++) {
        int m = m0 + wr * 64 + mf * 16 + rg * 4 + r;
        float v = acc[mf][nf][r] + bs;
        if (outF) outF[(size_t)m * 2048 + n] = v;
        if (outB) outB[(size_t)m * 2048 + n] = f2bf(v);
        if (outT) {
          int b_ = m >> 11, t_ = m & 2047, h_ = n >> 7, d_ = n & 127;
          outT[(((size_t)(b_ * 16 + h_) * 128 + d_) << 11) + t_] = f2bf(v);
        }
      }
    }
}

// ---------------- causal flash attention ----------------
// grid (T/64, B*H). 4 waves, each wave owns 16 q rows. KVBLK=64.
// Q (rope'd) from Qb[b][t][c]; K (rope'd) from Kb[b][t][c]; V^T from Vt[b][h][d][t].
// K/Vt LDS tiles XOR-swizzled (byte ^= (row&7)<<4) via pre-swizzled global source.
__global__ __launch_bounds__(256) void attn_fwd(const u16* __restrict__ Qb,
                                                const u16* __restrict__ Kb,
                                                const u16* __restrict__ Vt,
                                                u16* __restrict__ AO) {
  __shared__ __attribute__((aligned(16))) u16 Ks[64 * 128];   // 16KB, rows=kv (256B)
  __shared__ __attribute__((aligned(16))) u16 Vs[128 * 64];   // 16KB, rows=d  (128B)
  __shared__ __attribute__((aligned(16))) u16 Ps[4][16 * 64]; // per-wave P (128B rows)
  const int tid = threadIdx.x;
  const int lane = tid & 63;
  const int w = tid >> 6;
  const int r15 = lane & 15, rg = lane >> 4;
  const int bh = blockIdx.y;
  const int b = bh >> 4, h = bh & 15;
  const int q0 = blockIdx.x * 64;

  const int qrow = q0 + w * 16 + r15;
  bf16x8 qf[4];
#pragma unroll
  for (int ds = 0; ds < 4; ds++)
    qf[ds] = *(const bf16x8*)&Qb[(size_t)(b * 2048 + qrow) * 2048 + h * 128 + ds * 32 + rg * 8];

  f32x4 accO[8] = {};
  float m2[4], lsum[4];
#pragma unroll
  for (int r = 0; r < 4; r++) { m2[r] = -__builtin_inff(); lsum[r] = 0.f; }
  const float sc2 = 1.44269504088896f * 0.08838834764831845f;  // log2(e)/sqrt(128)

  const int ntiles = (q0 >> 6) + 1;
  for (int it = 0; it < ntiles; it++) {
    const int kv0 = it << 6;
    __syncthreads();
#pragma unroll
    for (int c = 0; c < 4; c++) {  // K tile: 64 rows x 256B
      int X = c * 4096 + tid * 16;
      int kvl = X >> 8, inner = X & 255;
      int linner = inner ^ ((kvl & 7) << 4);
      GLD16(Kb + (size_t)(b * 2048 + kv0 + kvl) * 2048 + h * 128 + (linner >> 1),
            (u16*)((char*)Ks + X));
    }
#pragma unroll
    for (int c = 0; c < 4; c++) {  // Vt tile: 128 rows x 128B
      int X = c * 4096 + tid * 16;
      int d = X >> 7, inner = X & 127;
      int linner = inner ^ ((d & 7) << 4);
      GLD16(Vt + ((size_t)(b * 16 + h) * 128 + d) * 2048 + kv0 + (linner >> 1),
            (u16*)((char*)Vs + X));
    }
    __syncthreads();

    // S = Q K^T (16 x 64 per wave)
    f32x4 s[4] = {};
#pragma unroll
    for (int ct = 0; ct < 4; ct++) {
      int kvl = ct * 16 + r15;
      const char* kbase = (const char*)Ks + kvl * 256;
      int sw = (kvl & 7) << 4;
#pragma unroll
      for (int ds = 0; ds < 4; ds++) {
        bf16x8 kf = *(const bf16x8*)(kbase + (((ds * 32 + rg * 8) << 1) ^ sw));
        s[ct] = __builtin_amdgcn_mfma_f32_16x16x32_bf16(qf[ds], kf, s[ct], 0, 0, 0);
      }
    }

    const bool masked = (kv0 == q0);
#pragma unroll
    for (int ct = 0; ct < 4; ct++) {
      int kv = kv0 + ct * 16 + r15;
#pragma unroll
      for (int r = 0; r < 4; r++) {
        float v = s[ct][r] * sc2;
        if (masked && kv > q0 + w * 16 + rg * 4 + r) v = -__builtin_inff();
        s[ct][r] = v;
      }
    }
    // online softmax (rows = rg*4+r, cols across 16 lanes of the rg-group)
#pragma unroll
    for (int r = 0; r < 4; r++) {
      float mx = fmaxf(fmaxf(s[0][r], s[1][r]), fmaxf(s[2][r], s[3][r]));
      mx = fmaxf(mx, __shfl_xor(mx, 1));
      mx = fmaxf(mx, __shfl_xor(mx, 2));
      mx = fmaxf(mx, __shfl_xor(mx, 4));
      mx = fmaxf(mx, __shfl_xor(mx, 8));
      float mnew = fmaxf(m2[r], mx);
      float alpha = exp2f(m2[r] - mnew);
      m2[r] = mnew;
      float rs = 0.f;
#pragma unroll
      for (int ct = 0; ct < 4; ct++) {
        float p = exp2f(s[ct][r] - mnew);
        s[ct][r] = p;
        rs += p;
      }
      rs += __shfl_xor(rs, 1);
      rs += __shfl_xor(rs, 2);
      rs += __shfl_xor(rs, 4);
      rs += __shfl_xor(rs, 8);
      lsum[r] = lsum[r] * alpha + rs;
#pragma unroll
      for (int dt = 0; dt < 8; dt++) accO[dt][r] *= alpha;
    }

    // write P (bf16) to per-wave LDS, swizzled
    {
      char* pb = (char*)Ps[w];
#pragma unroll
      for (int ct = 0; ct < 4; ct++) {
#pragma unroll
        for (int r = 0; r < 4; r++) {
          int prow = rg * 4 + r, pcol = ct * 16 + r15;
          *(u16*)(pb + prow * 128 + ((pcol << 1) ^ ((prow & 7) << 4))) = f2bf(s[ct][r]);
        }
      }
    }
    __syncthreads();

    // O += P V   (A = P[16x64], B = V[64x128] read from V^T tile rows)
#pragma unroll
    for (int ks = 0; ks < 2; ks++) {
      bf16x8 pa = *(const bf16x8*)((const char*)Ps[w] + r15 * 128 +
                                   (((ks * 32 + rg * 8) << 1) ^ ((r15 & 7) << 4)));
#pragma unroll
      for (int dt = 0; dt < 8; dt++) {
        int d = dt * 16 + r15;
        bf16x8 vf = *(const bf16x8*)((const char*)Vs + d * 128 +
                                     (((ks * 32 + rg * 8) << 1) ^ ((d & 7) << 4)));
        accO[dt] = __builtin_amdgcn_mfma_f32_16x16x32_bf16(pa, vf, accO[dt], 0, 0, 0);
      }
    }
  }

#pragma unroll
  for (int dt = 0; dt < 8; dt++) {
#pragma unroll
    for (int r = 0; r < 4; r++) {
      int q = q0 + w * 16 + rg * 4 + r;
      float v = accO[dt][r] / lsum[r];
      AO[(size_t)(b * 2048 + q) * 2048 + h * 128 + dt * 16 + r15] = f2bf(v);
    }
  }
}

extern "C" void kernel_launch(void* const* d_in, const int* in_sizes, int n_in,
                              void* d_out, int out_size, void* d_ws, size_t ws_size,
                              hipStream_t stream) {
  const float* x    = (const float*)d_in[0];
  const float* cosT = (const float*)d_in[1];
  const float* sinT = (const float*)d_in[2];
  const float* Wq   = (const float*)d_in[3];
  const float* bq   = (const float*)d_in[4];
  const float* Wk   = (const float*)d_in[5];
  const float* bk   = (const float*)d_in[6];
  const float* Wv   = (const float*)d_in[7];
  const float* bv   = (const float*)d_in[8];
  const float* Wo   = (const float*)d_in[9];
  const float* bo   = (const float*)d_in[10];

  float* out   = (float*)d_out;
  float* k_new = out + (size_t)16777216;   // B*T*C
  float* v_new = out + (size_t)33554432;

  char* ws = (char*)d_ws;
  u16* xb  = (u16*)(ws);                   // 33.5MB  (reused as AO later)
  u16* Wqb = (u16*)(ws + 33554432);        // 8.4MB each
  u16* Wkb = (u16*)(ws + 41943040);
  u16* Wvb = (u16*)(ws + 50331648);
  u16* Wob = (u16*)(ws + 58720256);
  u16* Qb  = (u16*)(ws + 67108864);        // 33.5MB
  u16* Kb  = (u16*)(ws + 100663296);       // 33.5MB
  u16* Vt  = (u16*)(ws + 134217728);       // 33.5MB  (end: 167772160)
  u16* AO  = xb;

  // fp32 -> bf16 staging
  cvt_bf16<<<16384, 256, 0, stream>>>(x, xb, 4194304);
  cvt_bf16<<<4096, 256, 0, stream>>>(Wq, Wqb, 1048576);
  cvt_bf16<<<4096, 256, 0, stream>>>(Wk, Wkb, 1048576);
  cvt_bf16<<<4096, 256, 0, stream>>>(Wv, Wvb, 1048576);
  cvt_bf16<<<4096, 256, 0, stream>>>(Wo, Wob, 1048576);

  // projections
  dim3 gg(16, 64);
  gemm_bt<<<gg, 256, 0, stream>>>(xb, Wqb, bq, nullptr, Qb, nullptr);
  gemm_bt<<<gg, 256, 0, stream>>>(xb, Wkb, bk, k_new, Kb, nullptr);
  gemm_bt<<<gg, 256, 0, stream>>>(xb, Wvb, bv, v_new, nullptr, Vt);

  // RoPE on Q and K (in place, full embedding dim)
  rope_ip<<<8192, 256, 0, stream>>>(Qb, cosT, sinT);
  rope_ip<<<8192, 256, 0, stream>>>(Kb, cosT, sinT);

  // causal flash attention -> AO (bf16 [B,T,C])
  attn_fwd<<<dim3(32, 64), 256, 0, stream>>>(Qb, Kb, Vt, AO);

  // output projection
  gemm_bt<<<gg, 256, 0, stream>>>(AO, Wob, bo, out, nullptr, nullptr);
}

// Round 3
// 908.538 us; speedup vs baseline: 1.0210x; 1.0210x over previous
//
#include <hip/hip_runtime.h>

typedef unsigned short u16;
typedef unsigned int u32;

typedef __attribute__((ext_vector_type(8))) short bf16x8;
typedef __attribute__((ext_vector_type(4))) float f32x4;

__device__ __forceinline__ u16 f2bf(float f) {
  u32 u = __builtin_bit_cast(u32, f);
  u32 r = (u + 0x7fffu + ((u >> 16) & 1u)) >> 16;
  return (u16)r;
}
__device__ __forceinline__ float bf2f(u16 h) {
  return __builtin_bit_cast(float, (u32)h << 16);
}

#define GLD16(g, l)                                       \
  __builtin_amdgcn_global_load_lds(                       \
      (__attribute__((address_space(1))) void*)(g),       \
      (__attribute__((address_space(3))) void*)(l), 16, 0, 0)

// ---------------- fp32 -> bf16 convert ----------------
__global__ __launch_bounds__(256) void cvt_bf16(const float* __restrict__ src,
                                                u16* __restrict__ dst, int n4) {
  int i = blockIdx.x * 256 + threadIdx.x;
  if (i >= n4) return;
  float4 v = ((const float4*)src)[i];
  ushort4 o;
  o.x = f2bf(v.x); o.y = f2bf(v.y); o.z = f2bf(v.z); o.w = f2bf(v.w);
  ((ushort4*)dst)[i] = o;
}

// ---------------- RoPE in place on bf16 [B,T,C], full-dim pairs (c, c+1024) ----
// Also multiplies by `scale` (used to fold log2(e)/sqrt(HD) into Q).
__global__ __launch_bounds__(256) void rope_ip(u16* buf,
                                               const float* __restrict__ cosT,
                                               const float* __restrict__ sinT,
                                               float scale) {
  int i = blockIdx.x * 256 + threadIdx.x;  // < B*T*256 = 2097152
  int c4 = (i & 255) << 2;                 // 0..1020
  size_t bt = (size_t)(i >> 8);
  int t = (int)(bt & 2047);
  u16* p1 = buf + bt * 2048 + c4;
  u16* p2 = p1 + 1024;
  ushort4 x1 = *(const ushort4*)p1;
  ushort4 x2 = *(const ushort4*)p2;
  float4 c1 = *(const float4*)&cosT[(size_t)t * 2048 + c4];
  float4 s1 = *(const float4*)&sinT[(size_t)t * 2048 + c4];
  float4 c2 = *(const float4*)&cosT[(size_t)t * 2048 + c4 + 1024];
  float4 s2 = *(const float4*)&sinT[(size_t)t * 2048 + c4 + 1024];
  float a0 = bf2f(x1.x), a1 = bf2f(x1.y), a2 = bf2f(x1.z), a3 = bf2f(x1.w);
  float b0 = bf2f(x2.x), b1 = bf2f(x2.y), b2 = bf2f(x2.z), b3 = bf2f(x2.w);
  ushort4 o1, o2;
  o1.x = f2bf((a0 * c1.x - b0 * s1.x) * scale);
  o1.y = f2bf((a1 * c1.y - b1 * s1.y) * scale);
  o1.z = f2bf((a2 * c1.z - b2 * s1.z) * scale);
  o1.w = f2bf((a3 * c1.w - b3 * s1.w) * scale);
  o2.x = f2bf((b0 * c2.x + a0 * s2.x) * scale);
  o2.y = f2bf((b1 * c2.y + a1 * s2.y) * scale);
  o2.z = f2bf((b2 * c2.z + a2 * s2.z) * scale);
  o2.w = f2bf((b3 * c2.w + a3 * s2.w) * scale);
  *(ushort4*)p1 = o1;
  *(ushort4*)p2 = o2;
}

// ---------------- bf16 GEMM: D[m][n] = sum_k A[m][k]*W[n][k] + bias[n] ----------
__global__ __launch_bounds__(256) void gemm_bt(const u16* __restrict__ A,
                                               const u16* __restrict__ Wm,
                                               const float* __restrict__ bias,
                                               float* __restrict__ outF,
                                               u16* __restrict__ outB,
                                               u16* __restrict__ outT) {
  __shared__ __attribute__((aligned(16))) u16 As[128 * 32];
  __shared__ __attribute__((aligned(16))) u16 Bs[128 * 32];
  const int tid = threadIdx.x;
  const int lane = tid & 63;
  const int w = tid >> 6;
  const int wr = w >> 1, wc = w & 1;
  const int m0 = blockIdx.y * 128, n0 = blockIdx.x * 128;
  const int r15 = lane & 15, rg = lane >> 4;

  f32x4 acc[4][4] = {};

  const int srow = tid >> 2;
  const int skoff = (tid & 3) << 3;
  for (int kt = 0; kt < 2048; kt += 32) {
    __syncthreads();
    const u16* gA = A + (size_t)(m0 + srow) * 2048 + kt + skoff;
    u16* lA = As + srow * 32 + skoff;  // byte offset = tid*16
    GLD16(gA, lA);
    GLD16(gA + (size_t)64 * 2048, lA + 64 * 32);
    const u16* gB = Wm + (size_t)(n0 + srow) * 2048 + kt + skoff;
    u16* lB = Bs + srow * 32 + skoff;
    GLD16(gB, lB);
    GLD16(gB + (size_t)64 * 2048, lB + 64 * 32);
    __syncthreads();
    bf16x8 a[4], b[4];
#pragma unroll
    for (int mf = 0; mf < 4; mf++)
      a[mf] = *(const bf16x8*)&As[(wr * 64 + mf * 16 + r15) * 32 + rg * 8];
#pragma unroll
    for (int nf = 0; nf < 4; nf++)
      b[nf] = *(const bf16x8*)&Bs[(wc * 64 + nf * 16 + r15) * 32 + rg * 8];
#pragma unroll
    for (int mf = 0; mf < 4; mf++)
#pragma unroll
      for (int nf = 0; nf < 4; nf++)
        acc[mf][nf] =
            __builtin_amdgcn_mfma_f32_16x16x32_bf16(a[mf], b[nf], acc[mf][nf], 0, 0, 0);
  }
#pragma unroll
  for (int mf = 0; mf < 4; mf++)
#pragma unroll
    for (int nf = 0; nf < 4; nf++) {
      int n = n0 + wc * 64 + nf * 16 + r15;
      float bs = bias[n];
#pragma unroll
      for (int r = 0; r < 4; r++) {
        int m = m0 + wr * 64 + mf * 16 + rg * 4 + r;
        float v = acc[mf][nf][r] + bs;
        if (outF) outF[(size_t)m * 2048 + n] = v;
        if (outB) outB[(size_t)m * 2048 + n] = f2bf(v);
        if (outT) {
          int b_ = m >> 11, t_ = m & 2047, h_ = n >> 7, d_ = n & 127;
          outT[(((size_t)(b_ * 16 + h_) * 128 + d_) << 11) + t_] = f2bf(v);
        }
      }
    }
}

// ---------------- causal flash attention ----------------
// grid (T/128, B*H), 512 threads. 8 waves, each wave owns 16 q rows. KVBLK=64.
// Q pre-scaled by log2(e)/sqrt(HD) in rope. K/V LDS tiles XOR-swizzled
// (byte ^= (row&7)<<4) via pre-swizzled global source address.
__global__ __launch_bounds__(512) void attn_fwd(const u16* __restrict__ Qb,
                                                const u16* __restrict__ Kb,
                                                const u16* __restrict__ Vt,
                                                u16* __restrict__ AO) {
  __shared__ __attribute__((aligned(16))) u16 Ks[64 * 128];   // 16KB, rows=kv (256B)
  __shared__ __attribute__((aligned(16))) u16 Vs[128 * 64];   // 16KB, rows=d  (128B)
  __shared__ __attribute__((aligned(16))) u16 Ps[8][16 * 64]; // 16KB per-wave P
  const int tid = threadIdx.x;
  const int lane = tid & 63;
  const int w = tid >> 6;
  const int r15 = lane & 15, rg = lane >> 4;
  const int bh = blockIdx.y;
  const int b = bh >> 4, h = bh & 15;
  const int q0 = (15 - blockIdx.x) * 128;  // heavy blocks first
  const int qw0 = q0 + w * 16;

  const int qrow = qw0 + r15;
  bf16x8 qf[4];
#pragma unroll
  for (int ds = 0; ds < 4; ds++)
    qf[ds] = *(const bf16x8*)&Qb[(size_t)(b * 2048 + qrow) * 2048 + h * 128 + ds * 32 + rg * 8];

  // hoisted staging pointers (advance by kv0 each tile)
  const u16* ksrc[2]; u16* kdst[2];
  const u16* vsrc[2]; u16* vdst[2];
#pragma unroll
  for (int c = 0; c < 2; c++) {
    int X = c * 8192 + tid * 16;
    int kvl = X >> 8;
    int linner = (X & 255) ^ ((kvl & 7) << 4);
    ksrc[c] = Kb + (size_t)(b * 2048 + kvl) * 2048 + h * 128 + (linner >> 1);
    kdst[c] = (u16*)((char*)Ks + X);
    int d = X >> 7;
    int lv = (X & 127) ^ ((d & 7) << 4);
    vsrc[c] = Vt + ((size_t)(b * 16 + h) * 128 + d) * 2048 + (lv >> 1);
    vdst[c] = (u16*)((char*)Vs + X);
  }

  f32x4 accO[8] = {};
  float m2[4], lsum[4];
#pragma unroll
  for (int r = 0; r < 4; r++) { m2[r] = -__builtin_inff(); lsum[r] = 0.f; }

  const int ntiles = (q0 >> 6) + 2;
  for (int it = 0; it < ntiles; it++) {
    const int kv0 = it << 6;
    __syncthreads();
#pragma unroll
    for (int c = 0; c < 2; c++) {
      GLD16(ksrc[c] + (size_t)kv0 * 2048, kdst[c]);
      GLD16(vsrc[c] + kv0, vdst[c]);
    }
    __syncthreads();

    if (kv0 > qw0 + 15) continue;  // wave fully masked (uniform branch)

    // S = Q K^T (16 x 64 per wave); Q pre-scaled to log2 units
    f32x4 s[4] = {};
#pragma unroll
    for (int ct = 0; ct < 4; ct++) {
      int kvl = ct * 16 + r15;
      const char* kbase = (const char*)Ks + kvl * 256;
      int sw = (kvl & 7) << 4;
#pragma unroll
      for (int ds = 0; ds < 4; ds++) {
        bf16x8 kf = *(const bf16x8*)(kbase + (((ds * 32 + rg * 8) << 1) ^ sw));
        s[ct] = __builtin_amdgcn_mfma_f32_16x16x32_bf16(qf[ds], kf, s[ct], 0, 0, 0);
      }
    }

    // mask needed whenever any column of the tile exceeds the wave's
    // SMALLEST row: kv0+63 > qw0  (NOT qw0+15 — that missed waves whose
    // strip ends exactly at the tile edge)
    if (kv0 + 63 > qw0) {
#pragma unroll
      for (int ct = 0; ct < 4; ct++) {
        int kv = kv0 + ct * 16 + r15;
#pragma unroll
        for (int r = 0; r < 4; r++)
          if (kv > qw0 + rg * 4 + r) s[ct][r] = -__builtin_inff();
      }
    }
    // online softmax (rows = rg*4+r, cols across 16 lanes of the rg-group)
#pragma unroll
    for (int r = 0; r < 4; r++) {
      float mx = fmaxf(fmaxf(s[0][r], s[1][r]), fmaxf(s[2][r], s[3][r]));
      mx = fmaxf(mx, __shfl_xor(mx, 1));
      mx = fmaxf(mx, __shfl_xor(mx, 2));
      mx = fmaxf(mx, __shfl_xor(mx, 4));
      mx = fmaxf(mx, __shfl_xor(mx, 8));
      float mnew = fmaxf(m2[r], mx);
      float alpha = exp2f(m2[r] - mnew);
      m2[r] = mnew;
      float rs = 0.f;
#pragma unroll
      for (int ct = 0; ct < 4; ct++) {
        float p = exp2f(s[ct][r] - mnew);
        s[ct][r] = p;
        rs += p;
      }
      rs += __shfl_xor(rs, 1);
      rs += __shfl_xor(rs, 2);
      rs += __shfl_xor(rs, 4);
      rs += __shfl_xor(rs, 8);
      lsum[r] = lsum[r] * alpha + rs;
#pragma unroll
      for (int dt = 0; dt < 8; dt++) accO[dt][r] *= alpha;
    }

    // write P (bf16) to per-wave LDS, swizzled (no barrier needed: per-wave)
    {
      char* pb = (char*)Ps[w];
#pragma unroll
      for (int ct = 0; ct < 4; ct++) {
#pragma unroll
        for (int r = 0; r < 4; r++) {
          int prow = rg * 4 + r, pcol = ct * 16 + r15;
          *(u16*)(pb + prow * 128 + ((pcol << 1) ^ ((prow & 7) << 4))) = f2bf(s[ct][r]);
        }
      }
    }

    // O += P V   (A = P[16x64], B = V[64x128] read from V^T tile rows)
#pragma unroll
    for (int ks = 0; ks < 2; ks++) {
      bf16x8 pa = *(const bf16x8*)((const char*)Ps[w] + r15 * 128 +
                                   (((ks * 32 + rg * 8) << 1) ^ ((r15 & 7) << 4)));
#pragma unroll
      for (int dt = 0; dt < 8; dt++) {
        int d = dt * 16 + r15;
        bf16x8 vf = *(const bf16x8*)((const char*)Vs + d * 128 +
                                     (((ks * 32 + rg * 8) << 1) ^ ((d & 7) << 4)));
        accO[dt] = __builtin_amdgcn_mfma_f32_16x16x32_bf16(pa, vf, accO[dt], 0, 0, 0);
      }
    }
  }

#pragma unroll
  for (int dt = 0; dt < 8; dt++) {
#pragma unroll
    for (int r = 0; r < 4; r++) {
      int q = qw0 + rg * 4 + r;
      float v = accO[dt][r] / lsum[r];
      AO[(size_t)(b * 2048 + q) * 2048 + h * 128 + dt * 16 + r15] = f2bf(v);
    }
  }
}

extern "C" void kernel_launch(void* const* d_in, const int* in_sizes, int n_in,
                              void* d_out, int out_size, void* d_ws, size_t ws_size,
                              hipStream_t stream) {
  const float* x    = (const float*)d_in[0];
  const float* cosT = (const float*)d_in[1];
  const float* sinT = (const float*)d_in[2];
  const float* Wq   = (const float*)d_in[3];
  const float* bq   = (const float*)d_in[4];
  const float* Wk   = (const float*)d_in[5];
  const float* bk   = (const float*)d_in[6];
  const float* Wv   = (const float*)d_in[7];
  const float* bv   = (const float*)d_in[8];
  const float* Wo   = (const float*)d_in[9];
  const float* bo   = (const float*)d_in[10];

  float* out   = (float*)d_out;
  float* k_new = out + (size_t)16777216;   // B*T*C
  float* v_new = out + (size_t)33554432;

  char* ws = (char*)d_ws;
  u16* xb  = (u16*)(ws);                   // 33.5MB  (reused as AO later)
  u16* Wqb = (u16*)(ws + 33554432);        // 8.4MB each
  u16* Wkb = (u16*)(ws + 41943040);
  u16* Wvb = (u16*)(ws + 50331648);
  u16* Wob = (u16*)(ws + 58720256);
  u16* Qb  = (u16*)(ws + 67108864);        // 33.5MB
  u16* Kb  = (u16*)(ws + 100663296);       // 33.5MB
  u16* Vt  = (u16*)(ws + 134217728);       // 33.5MB  (end: 167772160)
  u16* AO  = xb;

  // fp32 -> bf16 staging
  cvt_bf16<<<16384, 256, 0, stream>>>(x, xb, 4194304);
  cvt_bf16<<<4096, 256, 0, stream>>>(Wq, Wqb, 1048576);
  cvt_bf16<<<4096, 256, 0, stream>>>(Wk, Wkb, 1048576);
  cvt_bf16<<<4096, 256, 0, stream>>>(Wv, Wvb, 1048576);
  cvt_bf16<<<4096, 256, 0, stream>>>(Wo, Wob, 1048576);

  // projections
  dim3 gg(16, 64);
  gemm_bt<<<gg, 256, 0, stream>>>(xb, Wqb, bq, nullptr, Qb, nullptr);
  gemm_bt<<<gg, 256, 0, stream>>>(xb, Wkb, bk, k_new, Kb, nullptr);
  gemm_bt<<<gg, 256, 0, stream>>>(xb, Wvb, bv, v_new, nullptr, Vt);

  // RoPE: Q gets scale log2(e)/sqrt(128) folded in; K plain
  const float sc2 = 1.44269504088896f * 0.08838834764831845f;
  rope_ip<<<8192, 256, 0, stream>>>(Qb, cosT, sinT, sc2);
  rope_ip<<<8192, 256, 0, stream>>>(Kb, cosT, sinT, 1.0f);

  // causal flash attention -> AO (bf16 [B,T,C])
  attn_fwd<<<dim3(16, 64), 512, 0, stream>>>(Qb, Kb, Vt, AO);

  // output projection
  gemm_bt<<<gg, 256, 0, stream>>>(AO, Wob, bo, out, nullptr, nullptr);
}

// Round 4
// 715.239 us; speedup vs baseline: 1.2970x; 1.2703x over previous
//
#include <hip/hip_runtime.h>

typedef unsigned short u16;
typedef unsigned int u32;

typedef __attribute__((ext_vector_type(8))) short bf16x8;
typedef __attribute__((ext_vector_type(4))) float f32x4;
typedef __attribute__((ext_vector_type(16))) float f32x16;
typedef __attribute__((ext_vector_type(4))) u32 u32x4;

__device__ __forceinline__ u16 f2bf(float f) {
  u32 u = __builtin_bit_cast(u32, f);
  u32 r = (u + 0x7fffu + ((u >> 16) & 1u)) >> 16;
  return (u16)r;
}
__device__ __forceinline__ float bf2f(u16 h) {
  return __builtin_bit_cast(float, (u32)h << 16);
}
__device__ __forceinline__ u32 cvtpk(float lo, float hi) {
  u32 d;
  asm("v_cvt_pk_bf16_f32 %0, %1, %2" : "=v"(d) : "v"(lo), "v"(hi));
  return d;
}
// v_permlane32_swap_b32: a.hi <-> b.lo.  After: a={a.lo, b.lo}, b={a.hi, b.hi}
__device__ __forceinline__ void plswap(u32& a, u32& b) {
  asm("v_permlane32_swap_b32 %0, %1" : "+v"(a), "+v"(b));
}

#define GLD16(g, l)                                       \
  __builtin_amdgcn_global_load_lds(                       \
      (__attribute__((address_space(1))) void*)(g),       \
      (__attribute__((address_space(3))) void*)(l), 16, 0, 0)

// ---------------- fp32 -> bf16 convert ----------------
__global__ __launch_bounds__(256) void cvt_bf16(const float* __restrict__ src,
                                                u16* __restrict__ dst, int n4) {
  int i = blockIdx.x * 256 + threadIdx.x;
  if (i >= n4) return;
  float4 v = ((const float4*)src)[i];
  ushort4 o;
  o.x = f2bf(v.x); o.y = f2bf(v.y); o.z = f2bf(v.z); o.w = f2bf(v.w);
  ((ushort4*)dst)[i] = o;
}

// ---------------- RoPE in place on bf16 [B,T,C], full-dim pairs (c, c+1024) ----
__global__ __launch_bounds__(256) void rope_ip(u16* buf,
                                               const float* __restrict__ cosT,
                                               const float* __restrict__ sinT,
                                               float scale) {
  int i = blockIdx.x * 256 + threadIdx.x;  // < B*T*256 = 2097152
  int c4 = (i & 255) << 2;                 // 0..1020
  size_t bt = (size_t)(i >> 8);
  int t = (int)(bt & 2047);
  u16* p1 = buf + bt * 2048 + c4;
  u16* p2 = p1 + 1024;
  ushort4 x1 = *(const ushort4*)p1;
  ushort4 x2 = *(const ushort4*)p2;
  float4 c1 = *(const float4*)&cosT[(size_t)t * 2048 + c4];
  float4 s1 = *(const float4*)&sinT[(size_t)t * 2048 + c4];
  float4 c2 = *(const float4*)&cosT[(size_t)t * 2048 + c4 + 1024];
  float4 s2 = *(const float4*)&sinT[(size_t)t * 2048 + c4 + 1024];
  float a0 = bf2f(x1.x), a1 = bf2f(x1.y), a2 = bf2f(x1.z), a3 = bf2f(x1.w);
  float b0 = bf2f(x2.x), b1 = bf2f(x2.y), b2 = bf2f(x2.z), b3 = bf2f(x2.w);
  ushort4 o1, o2;
  o1.x = f2bf((a0 * c1.x - b0 * s1.x) * scale);
  o1.y = f2bf((a1 * c1.y - b1 * s1.y) * scale);
  o1.z = f2bf((a2 * c1.z - b2 * s1.z) * scale);
  o1.w = f2bf((a3 * c1.w - b3 * s1.w) * scale);
  o2.x = f2bf((b0 * c2.x + a0 * s2.x) * scale);
  o2.y = f2bf((b1 * c2.y + a1 * s2.y) * scale);
  o2.z = f2bf((b2 * c2.z + a2 * s2.z) * scale);
  o2.w = f2bf((b3 * c2.w + a3 * s2.w) * scale);
  *(ushort4*)p1 = o1;
  *(ushort4*)p2 = o2;
}

// ---------------- bf16 GEMM: D[m][n] = sum_k A[m][k]*W[n][k] + bias[n] ----------
__global__ __launch_bounds__(256) void gemm_bt(const u16* __restrict__ A,
                                               const u16* __restrict__ Wm,
                                               const float* __restrict__ bias,
                                               float* __restrict__ outF,
                                               u16* __restrict__ outB,
                                               u16* __restrict__ outT) {
  __shared__ __attribute__((aligned(16))) u16 As[128 * 32];
  __shared__ __attribute__((aligned(16))) u16 Bs[128 * 32];
  const int tid = threadIdx.x;
  const int lane = tid & 63;
  const int w = tid >> 6;
  const int wr = w >> 1, wc = w & 1;
  const int m0 = blockIdx.y * 128, n0 = blockIdx.x * 128;
  const int r15 = lane & 15, rg = lane >> 4;

  f32x4 acc[4][4] = {};

  const int srow = tid >> 2;
  const int skoff = (tid & 3) << 3;
  for (int kt = 0; kt < 2048; kt += 32) {
    __syncthreads();
    const u16* gA = A + (size_t)(m0 + srow) * 2048 + kt + skoff;
    u16* lA = As + srow * 32 + skoff;  // byte offset = tid*16
    GLD16(gA, lA);
    GLD16(gA + (size_t)64 * 2048, lA + 64 * 32);
    const u16* gB = Wm + (size_t)(n0 + srow) * 2048 + kt + skoff;
    u16* lB = Bs + srow * 32 + skoff;
    GLD16(gB, lB);
    GLD16(gB + (size_t)64 * 2048, lB + 64 * 32);
    __syncthreads();
    bf16x8 a[4], b[4];
#pragma unroll
    for (int mf = 0; mf < 4; mf++)
      a[mf] = *(const bf16x8*)&As[(wr * 64 + mf * 16 + r15) * 32 + rg * 8];
#pragma unroll
    for (int nf = 0; nf < 4; nf++)
      b[nf] = *(const bf16x8*)&Bs[(wc * 64 + nf * 16 + r15) * 32 + rg * 8];
#pragma unroll
    for (int mf = 0; mf < 4; mf++)
#pragma unroll
      for (int nf = 0; nf < 4; nf++)
        acc[mf][nf] =
            __builtin_amdgcn_mfma_f32_16x16x32_bf16(a[mf], b[nf], acc[mf][nf], 0, 0, 0);
  }
#pragma unroll
  for (int mf = 0; mf < 4; mf++)
#pragma unroll
    for (int nf = 0; nf < 4; nf++) {
      int n = n0 + wc * 64 + nf * 16 + r15;
      float bs = bias[n];
#pragma unroll
      for (int r = 0; r < 4; r++) {
        int m = m0 + wr * 64 + mf * 16 + rg * 4 + r;
        float v = acc[mf][nf][r] + bs;
        if (outF) outF[(size_t)m * 2048 + n] = v;
        if (outB) outB[(size_t)m * 2048 + n] = f2bf(v);
        if (outT) {
          int b_ = m >> 11, t_ = m & 2047, h_ = n >> 7, d_ = n & 127;
          outT[(((size_t)(b_ * 16 + h_) * 128 + d_) << 11) + t_] = f2bf(v);
        }
      }
    }
}

// ---------------- causal flash attention, 32x32 swapped-QK structure ----------
// grid (T/128, B*H), 256 threads = 4 waves, each wave owns 32 q rows. KVBLK=64.
// Q pre-scaled by log2(e)/sqrt(HD). K/V double-buffered in LDS, 256B rows,
// 16-slot XOR swizzle (byte ^= (row&15)<<4) via pre-swizzled global source.
// S^T = mfma(K, Q) so each lane holds one q-row (q = lane&31) fully in-register;
// P -> PV A-fragments via cvt_pk_bf16 + permlane32_swap (T12). Defer-max (T13).
__global__ __launch_bounds__(256, 2) void attn_fwd(const u16* __restrict__ Qb,
                                                   const u16* __restrict__ Kb,
                                                   const u16* __restrict__ Vt,
                                                   u16* __restrict__ AO) {
  // K: logical [64 kv][128 d], physical row=kv, 256B/row, slot-swizzled
  // V: logical [128 d][64 kv] stored as row=d&63, halves side by side (256B/row)
  __shared__ __attribute__((aligned(16))) u16 Ks[2][64 * 128];
  __shared__ __attribute__((aligned(16))) u16 Vs[2][64 * 128];
  const int tid = threadIdx.x;
  const int lane = tid & 63;
  const int w = tid >> 6;                    // 0..3
  const int c31 = lane & 31, hi = lane >> 5;
  const int bh = blockIdx.y;
  const int b = bh >> 4, h = bh & 15;
  const int q0 = (15 - blockIdx.x) * 128;    // heavy blocks first
  const int qw0 = q0 + w * 32;
  const int q = qw0 + c31;                   // this lane's q row

  // Q fragments: B-operand of mfma(K,Q). col=lane&31=q, k=d=ks*16+hi*8+e
  bf16x8 qreg[8];
  {
    const u16* qp = Qb + ((size_t)(b * 2048 + q)) * 2048 + h * 128 + hi * 8;
#pragma unroll
    for (int ks = 0; ks < 8; ks++) qreg[ks] = *(const bf16x8*)(qp + ks * 16);
  }

  // staging pointers (pre-swizzled source, linear LDS dest). 4 K + 4 V chunks.
  const u16* ksrc[4];
  const u16* vsrc[4];
  int xoff[4];
#pragma unroll
  for (int c = 0; c < 4; c++) {
    int X = c * 4096 + tid * 16;             // dest byte in 16KB tile
    int row = X >> 8, phys = X & 255;
    int lg = phys ^ ((row & 15) << 4);       // logical byte within row
    xoff[c] = X;
    ksrc[c] = Kb + (size_t)(b * 2048 + row) * 2048 + h * 128 + (lg >> 1);
    int vd = row + ((lg >> 7) << 6);         // d = row + 64*half
    int kvb = lg & 127;
    vsrc[c] = Vt + ((size_t)(b * 16 + h) * 128 + vd) * 2048 + (kvb >> 1);
  }

  f32x16 accO[4] = {};
  float m_run = -__builtin_inff(), l_run = 0.f;

  const int ntiles = (q0 >> 6) + 2;

  // prologue: stage tile 0 into buffer 0, advance pointers
#pragma unroll
  for (int c = 0; c < 4; c++) {
    GLD16(ksrc[c], (char*)Ks + xoff[c]);
    GLD16(vsrc[c], (char*)Vs + xoff[c]);
    ksrc[c] += (size_t)64 * 2048;
    vsrc[c] += 64;
  }

  for (int it = 0; it < ntiles; it++) {
    const int kv0 = it << 6;
    const int buf = it & 1;
    __syncthreads();  // waits prev stage (implicit vmcnt0) + orders buffers
    if (it + 1 < ntiles) {
      const int nb = buf ^ 1;
#pragma unroll
      for (int c = 0; c < 4; c++) {
        GLD16(ksrc[c], (char*)Ks + nb * 16384 + xoff[c]);
        GLD16(vsrc[c], (char*)Vs + nb * 16384 + xoff[c]);
        ksrc[c] += (size_t)64 * 2048;
        vsrc[c] += 64;
      }
    }
    if (kv0 > qw0 + 31) continue;  // wave fully masked (uniform per wave)

    // ---- S^T[64kv x 32q] = K * Q^T : 2 kv-tiles x 8 k-steps of 32x32x16
    f32x16 sT[2] = {};
    {
      const char* kb = (const char*)Ks + buf * 16384;
#pragma unroll
      for (int kvt = 0; kvt < 2; kvt++) {
        int krow = kvt * 32 + c31;
        const char* kr = kb + krow * 256;
        int sw = (krow & 15) << 4;
#pragma unroll
        for (int ks = 0; ks < 8; ks++) {
          bf16x8 kf = *(const bf16x8*)(kr + ((ks * 32 + hi * 16) ^ sw));
          sT[kvt] = __builtin_amdgcn_mfma_f32_32x32x16_bf16(kf, qreg[ks], sT[kvt], 0, 0, 0);
        }
      }
    }

    // causal mask: kv(reg r) = kv0 + kvt*32 + (r&3) + 8*(r>>2) + 4*hi
    if (kv0 + 63 > qw0) {
#pragma unroll
      for (int kvt = 0; kvt < 2; kvt++)
#pragma unroll
        for (int r = 0; r < 16; r++) {
          int kv = kv0 + kvt * 32 + (r & 3) + 8 * (r >> 2) + 4 * hi;
          if (kv > q) sT[kvt][r] = -__builtin_inff();
        }
    }

    // ---- in-register softmax over this lane's 32 values + partner half
    float tm[16];
#pragma unroll
    for (int r = 0; r < 16; r++) tm[r] = fmaxf(sT[0][r], sT[1][r]);
#pragma unroll
    for (int st = 8; st > 0; st >>= 1)
#pragma unroll
      for (int r = 0; r < st; r++) tm[r] = fmaxf(tm[r], tm[r + st]);
    float pmax = tm[0];
    pmax = fmaxf(pmax, __shfl_xor(pmax, 32));

    if (!__all(pmax - m_run <= 8.0f)) {  // defer-max: rescale only when needed
      float mnew = fmaxf(m_run, pmax);
      float alpha = exp2f(m_run - mnew);
      m_run = mnew;
      l_run *= alpha;
#pragma unroll
      for (int r = 0; r < 16; r++) {
        float ar = __shfl(alpha, (r & 3) + 8 * (r >> 2) + 4 * hi);
#pragma unroll
        for (int dt = 0; dt < 4; dt++) accO[dt][r] *= ar;
      }
    }

    float a0 = 0.f, a1 = 0.f, a2 = 0.f, a3 = 0.f;
#pragma unroll
    for (int kvt = 0; kvt < 2; kvt++)
#pragma unroll
      for (int r = 0; r < 16; r++) {
        float p = exp2f(sT[kvt][r] - m_run);
        sT[kvt][r] = p;
        if ((r & 3) == 0) a0 += p; else if ((r & 3) == 1) a1 += p;
        else if ((r & 3) == 2) a2 += p; else a3 += p;
      }
    float rs = (a0 + a1) + (a2 + a3);
    rs += __shfl_xor(rs, 32);
    l_run += rs;

    // ---- P -> PV A-fragments: 16 cvt_pk + 8 permlane32_swap
    u32x4 pa[4];
#pragma unroll
    for (int kvt = 0; kvt < 2; kvt++)
#pragma unroll
      for (int hf = 0; hf < 2; hf++) {
        u32 wA0 = cvtpk(sT[kvt][hf * 8 + 0], sT[kvt][hf * 8 + 1]);
        u32 wA1 = cvtpk(sT[kvt][hf * 8 + 4], sT[kvt][hf * 8 + 5]);
        u32 wB0 = cvtpk(sT[kvt][hf * 8 + 2], sT[kvt][hf * 8 + 3]);
        u32 wB1 = cvtpk(sT[kvt][hf * 8 + 6], sT[kvt][hf * 8 + 7]);
        plswap(wA0, wA1);
        plswap(wB0, wB1);
        pa[kvt * 2 + hf] = (u32x4){wA0, wB0, wA1, wB1};
      }

    // ---- O += P V : 4 d-tiles x 4 kv-slices of 32x32x16
    {
      const char* vb = (const char*)Vs + buf * 16384;
#pragma unroll
      for (int dt = 0; dt < 4; dt++) {
        int vrow = (dt & 1) * 32 + c31;
        const char* vr = vb + vrow * 256;
        int sw = (vrow & 15) << 4;
        int hsel = (dt >> 1) * 128;
#pragma unroll
        for (int ks = 0; ks < 4; ks++) {
          bf16x8 vf = *(const bf16x8*)(vr + ((hsel + ks * 32 + hi * 16) ^ sw));
          bf16x8 paf = __builtin_bit_cast(bf16x8, pa[ks]);
          accO[dt] = __builtin_amdgcn_mfma_f32_32x32x16_bf16(paf, vf, accO[dt], 0, 0, 0);
        }
      }
    }
  }

  // ---- epilogue: normalize by l (per-q, broadcast per reg) and store
  float linv = 1.0f / l_run;
#pragma unroll
  for (int r = 0; r < 16; r++) {
    int crow = (r & 3) + 8 * (r >> 2) + 4 * hi;
    float lr = __shfl(linv, crow);
    int qq = qw0 + crow;
    u16* op = AO + (size_t)(b * 2048 + qq) * 2048 + h * 128 + c31;
#pragma unroll
    for (int dt = 0; dt < 4; dt++) op[dt * 32] = f2bf(accO[dt][r] * lr);
  }
}

extern "C" void kernel_launch(void* const* d_in, const int* in_sizes, int n_in,
                              void* d_out, int out_size, void* d_ws, size_t ws_size,
                              hipStream_t stream) {
  const float* x    = (const float*)d_in[0];
  const float* cosT = (const float*)d_in[1];
  const float* sinT = (const float*)d_in[2];
  const float* Wq   = (const float*)d_in[3];
  const float* bq   = (const float*)d_in[4];
  const float* Wk   = (const float*)d_in[5];
  const float* bk   = (const float*)d_in[6];
  const float* Wv   = (const float*)d_in[7];
  const float* bv   = (const float*)d_in[8];
  const float* Wo   = (const float*)d_in[9];
  const float* bo   = (const float*)d_in[10];

  float* out   = (float*)d_out;
  float* k_new = out + (size_t)16777216;   // B*T*C
  float* v_new = out + (size_t)33554432;

  char* ws = (char*)d_ws;
  u16* xb  = (u16*)(ws);                   // 33.5MB  (reused as AO later)
  u16* Wqb = (u16*)(ws + 33554432);        // 8.4MB each
  u16* Wkb = (u16*)(ws + 41943040);
  u16* Wvb = (u16*)(ws + 50331648);
  u16* Wob = (u16*)(ws + 58720256);
  u16* Qb  = (u16*)(ws + 67108864);        // 33.5MB
  u16* Kb  = (u16*)(ws + 100663296);       // 33.5MB
  u16* Vt  = (u16*)(ws + 134217728);       // 33.5MB  (end: 167772160)
  u16* AO  = xb;

  // fp32 -> bf16 staging
  cvt_bf16<<<16384, 256, 0, stream>>>(x, xb, 4194304);
  cvt_bf16<<<4096, 256, 0, stream>>>(Wq, Wqb, 1048576);
  cvt_bf16<<<4096, 256, 0, stream>>>(Wk, Wkb, 1048576);
  cvt_bf16<<<4096, 256, 0, stream>>>(Wv, Wvb, 1048576);
  cvt_bf16<<<4096, 256, 0, stream>>>(Wo, Wob, 1048576);

  // projections
  dim3 gg(16, 64);
  gemm_bt<<<gg, 256, 0, stream>>>(xb, Wqb, bq, nullptr, Qb, nullptr);
  gemm_bt<<<gg, 256, 0, stream>>>(xb, Wkb, bk, k_new, Kb, nullptr);
  gemm_bt<<<gg, 256, 0, stream>>>(xb, Wvb, bv, v_new, nullptr, Vt);

  // RoPE: Q gets scale log2(e)/sqrt(128) folded in; K plain
  const float sc2 = 1.44269504088896f * 0.08838834764831845f;
  rope_ip<<<8192, 256, 0, stream>>>(Qb, cosT, sinT, sc2);
  rope_ip<<<8192, 256, 0, stream>>>(Kb, cosT, sinT, 1.0f);

  // causal flash attention -> AO (bf16 [B,T,C])
  attn_fwd<<<dim3(16, 64), 256, 0, stream>>>(Qb, Kb, Vt, AO);

  // output projection
  gemm_bt<<<gg, 256, 0, stream>>>(AO, Wob, bo, out, nullptr, nullptr);
}

// Round 5
// 576.339 us; speedup vs baseline: 1.6095x; 1.2410x over previous
//
#include <hip/hip_runtime.h>

typedef unsigned short u16;
typedef unsigned int u32;

typedef __attribute__((ext_vector_type(8))) short bf16x8;
typedef __attribute__((ext_vector_type(4))) float f32x4;
typedef __attribute__((ext_vector_type(16))) float f32x16;
typedef __attribute__((ext_vector_type(4))) u32 u32x4;

__device__ __forceinline__ u16 f2bf(float f) {
  u32 u = __builtin_bit_cast(u32, f);
  u32 r = (u + 0x7fffu + ((u >> 16) & 1u)) >> 16;
  return (u16)r;
}
__device__ __forceinline__ float bf2f(u16 h) {
  return __builtin_bit_cast(float, (u32)h << 16);
}
__device__ __forceinline__ u32 cvtpk(float lo, float hi) {
  u32 d;
  asm("v_cvt_pk_bf16_f32 %0, %1, %2" : "=v"(d) : "v"(lo), "v"(hi));
  return d;
}
// v_permlane32_swap_b32: a.hi <-> b.lo.  After: a={a.lo, b.lo}, b={a.hi, b.hi}
__device__ __forceinline__ void plswap(u32& a, u32& b) {
  asm("v_permlane32_swap_b32 %0, %1" : "+v"(a), "+v"(b));
}

#define GLD16(g, l)                                       \
  __builtin_amdgcn_global_load_lds(                       \
      (__attribute__((address_space(1))) void*)(g),       \
      (__attribute__((address_space(3))) void*)(l), 16, 0, 0)

#define WAITV8() asm volatile("s_waitcnt vmcnt(8)" ::: "memory")
#define WAITV0() asm volatile("s_waitcnt vmcnt(0)" ::: "memory")
#define BARF()                               \
  {                                          \
    asm volatile("" ::: "memory");           \
    __builtin_amdgcn_s_barrier();            \
    asm volatile("" ::: "memory");           \
  }

// ---------------- fp32 -> bf16 convert ----------------
__global__ __launch_bounds__(256) void cvt_bf16(const float* __restrict__ src,
                                                u16* __restrict__ dst, int n4) {
  int i = blockIdx.x * 256 + threadIdx.x;
  if (i >= n4) return;
  float4 v = ((const float4*)src)[i];
  ushort4 o;
  o.x = f2bf(v.x); o.y = f2bf(v.y); o.z = f2bf(v.z); o.w = f2bf(v.w);
  ((ushort4*)dst)[i] = o;
}

// ---------------- RoPE in place on bf16 [B,T,C], full-dim pairs (c, c+1024) ----
__global__ __launch_bounds__(256) void rope_ip(u16* buf,
                                               const float* __restrict__ cosT,
                                               const float* __restrict__ sinT,
                                               float scale) {
  int i = blockIdx.x * 256 + threadIdx.x;  // < B*T*256 = 2097152
  int c4 = (i & 255) << 2;                 // 0..1020
  size_t bt = (size_t)(i >> 8);
  int t = (int)(bt & 2047);
  u16* p1 = buf + bt * 2048 + c4;
  u16* p2 = p1 + 1024;
  ushort4 x1 = *(const ushort4*)p1;
  ushort4 x2 = *(const ushort4*)p2;
  float4 c1 = *(const float4*)&cosT[(size_t)t * 2048 + c4];
  float4 s1 = *(const float4*)&sinT[(size_t)t * 2048 + c4];
  float4 c2 = *(const float4*)&cosT[(size_t)t * 2048 + c4 + 1024];
  float4 s2 = *(const float4*)&sinT[(size_t)t * 2048 + c4 + 1024];
  float a0 = bf2f(x1.x), a1 = bf2f(x1.y), a2 = bf2f(x1.z), a3 = bf2f(x1.w);
  float b0 = bf2f(x2.x), b1 = bf2f(x2.y), b2 = bf2f(x2.z), b3 = bf2f(x2.w);
  ushort4 o1, o2;
  o1.x = f2bf((a0 * c1.x - b0 * s1.x) * scale);
  o1.y = f2bf((a1 * c1.y - b1 * s1.y) * scale);
  o1.z = f2bf((a2 * c1.z - b2 * s1.z) * scale);
  o1.w = f2bf((a3 * c1.w - b3 * s1.w) * scale);
  o2.x = f2bf((b0 * c2.x + a0 * s2.x) * scale);
  o2.y = f2bf((b1 * c2.y + a1 * s2.y) * scale);
  o2.z = f2bf((b2 * c2.z + a2 * s2.z) * scale);
  o2.w = f2bf((b3 * c2.w + a3 * s2.w) * scale);
  *(ushort4*)p1 = o1;
  *(ushort4*)p2 = o2;
}

// ---------------- bf16 GEMM: D[m][n] = sum_k A[m][k]*W[n][k] + bias[n] ----------
// 256x256 tile, BK=64, 8 waves (2M x 4N), per-wave 128x64. LDS 128KB double-buffered.
// Counted vmcnt(8): one K-tile of global_load_lds always in flight across waits.
// LDS rows 128B, XOR swizzle byte ^= ((row&7)<<4) via pre-swizzled global source.
__global__ __launch_bounds__(512, 2) void gemm_bt(const u16* __restrict__ A,
                                                  const u16* __restrict__ Wm,
                                                  const float* __restrict__ bias,
                                                  float* __restrict__ outF,
                                                  u16* __restrict__ outB,
                                                  u16* __restrict__ outT) {
  // regions (bytes): A slot0 @0, A slot1 @32768, B slot0 @65536, B slot1 @98304
  __shared__ __attribute__((aligned(16))) char L[131072];
  const int tid = threadIdx.x;
  const int lane = tid & 63;
  const int w = tid >> 6;        // 0..7
  const int wr = w >> 2;         // 0..1 : M half
  const int wcn = w & 3;         // 0..3 : N quarter
  const int m0 = blockIdx.y * 256, n0 = blockIdx.x * 256;
  const int r15 = lane & 15, rg = lane >> 4;
  const int sw = (r15 & 7) << 4;

  // staging: thread writes LDS dest bytes c*8192 + tid*16 within a 32KB region.
  // dest row = c*64 + (tid>>3), inner byte = (tid&7)*16, logical = inner ^ ((row&7)<<4)
  const int trow = tid >> 3;
  const int tlog = ((tid & 7) << 4) ^ ((trow & 7) << 4);
  const u16* pA = A + (size_t)(m0 + trow) * 2048 + (tlog >> 1);
  const u16* pB = Wm + (size_t)(n0 + trow) * 2048 + (tlog >> 1);
  char* dA = L + tid * 16;
  char* dB = L + 65536 + tid * 16;
  // chunk c: +c*131072 elements in global (64 rows), +c*8192 bytes in LDS

#define STAGE(dst, src, koff)                                   \
  {                                                             \
    _Pragma("unroll")                                           \
    for (int c = 0; c < 4; c++)                                 \
      GLD16((src) + (size_t)c * 131072 + (koff), (dst) + c * 8192); \
  }

  const char* aBase = L + wr * 16384;
  const char* bBase = L + 65536 + (wcn >> 1) * 16384 + (wcn & 1) * 8192;

  f32x4 acc[8][4] = {};
  bf16x8 ar[4][2], br[2][2][2];

  auto LD_A = [&](int mq, int soff) {
#pragma unroll
    for (int mf = 0; mf < 4; mf++)
#pragma unroll
      for (int ks = 0; ks < 2; ks++) {
        int row = mq * 64 + mf * 16 + r15;
        ar[mf][ks] = *(const bf16x8*)(aBase + soff + row * 128 +
                                      ((ks * 64 + rg * 16) ^ sw));
      }
  };
  auto LD_B = [&](int nq, int soff) {
#pragma unroll
    for (int nf = 0; nf < 2; nf++)
#pragma unroll
      for (int ks = 0; ks < 2; ks++) {
        int row = nq * 32 + nf * 16 + r15;
        br[nq][nf][ks] = *(const bf16x8*)(bBase + soff + row * 128 +
                                          ((ks * 64 + rg * 16) ^ sw));
      }
  };
  auto QUAD = [&](int mq, int nq) {
#pragma unroll
    for (int mf = 0; mf < 4; mf++)
#pragma unroll
      for (int nf = 0; nf < 2; nf++)
#pragma unroll
        for (int ks = 0; ks < 2; ks++)
          acc[mq * 4 + mf][nq * 2 + nf] = __builtin_amdgcn_mfma_f32_16x16x32_bf16(
              ar[mf][ks], br[nq][nf][ks], acc[mq * 4 + mf][nq * 2 + nf], 0, 0, 0);
  };
  auto COMPUTE = [&](int soff) {
    LD_A(0, soff);
    LD_B(0, soff);
    LD_B(1, soff);
    __builtin_amdgcn_s_setprio(1);
    QUAD(0, 0);
    QUAD(0, 1);
    __builtin_amdgcn_s_setprio(0);
    LD_A(1, soff);
    __builtin_amdgcn_s_setprio(1);
    QUAD(1, 1);
    QUAD(1, 0);
    __builtin_amdgcn_s_setprio(0);
  };

  // prologue: tiles 0 (slot0) and 1 (slot1)
  STAGE(dA, pA, 0);
  STAGE(dB, pB, 0);
  asm volatile("" ::: "memory");
  STAGE(dA + 32768, pA, 64);
  STAGE(dB + 32768, pB, 64);
  WAITV8();  // tile0 complete; tile1's 8 in flight
  BARF();

  for (int it = 0; it < 16; it++) {
    // ---- K-tile 2it (slot0) ----
    COMPUTE(0);
    BARF();  // all waves done reading slot0 (ds_reads drained by MFMA operand waits)
    if (it < 15) {
      STAGE(dA, pA, (2 * it + 2) * 64);
      STAGE(dB, pB, (2 * it + 2) * 64);
      WAITV8();  // drains slot1's 8; leaves the 8 just issued
    } else {
      WAITV0();
    }
    BARF();
    // ---- K-tile 2it+1 (slot1) ----
    COMPUTE(32768);
    if (it < 15) {
      BARF();  // all waves done reading slot1
      STAGE(dA + 32768, pA, (2 * it + 3) * 64);
      STAGE(dB + 32768, pB, (2 * it + 3) * 64);
      WAITV8();  // drains slot0-next; leaves slot1-next in flight
      BARF();
    }
  }

  // epilogue
#pragma unroll
  for (int am = 0; am < 8; am++)
#pragma unroll
    for (int bn = 0; bn < 4; bn++) {
      int n = n0 + wcn * 64 + bn * 16 + r15;
      float bs = bias[n];
#pragma unroll
      for (int i = 0; i < 4; i++) {
        int m = m0 + wr * 128 + am * 16 + rg * 4 + i;
        float v = acc[am][bn][i] + bs;
        if (outF) outF[(size_t)m * 2048 + n] = v;
        if (outB) outB[(size_t)m * 2048 + n] = f2bf(v);
        if (outT) {
          int b_ = m >> 11, t_ = m & 2047, h_ = n >> 7, d_ = n & 127;
          outT[(((size_t)(b_ * 16 + h_) * 128 + d_) << 11) + t_] = f2bf(v);
        }
      }
    }
#undef STAGE
}

// ---------------- causal flash attention, 32x32 swapped-QK structure ----------
// grid (T/128, B*H), 256 threads = 4 waves, each wave owns 32 q rows. KVBLK=64.
// Q pre-scaled by log2(e)/sqrt(HD). K/V double-buffered in LDS, 256B rows,
// 16-slot XOR swizzle (byte ^= (row&15)<<4) via pre-swizzled global source.
// S^T = mfma(K, Q) so each lane holds one q-row (q = lane&31) fully in-register;
// P -> PV A-fragments via cvt_pk_bf16 + permlane32_swap (T12). Defer-max (T13).
__global__ __launch_bounds__(256, 2) void attn_fwd(const u16* __restrict__ Qb,
                                                   const u16* __restrict__ Kb,
                                                   const u16* __restrict__ Vt,
                                                   u16* __restrict__ AO) {
  __shared__ __attribute__((aligned(16))) u16 Ks[2][64 * 128];
  __shared__ __attribute__((aligned(16))) u16 Vs[2][64 * 128];
  const int tid = threadIdx.x;
  const int lane = tid & 63;
  const int w = tid >> 6;                    // 0..3
  const int c31 = lane & 31, hi = lane >> 5;
  const int bh = blockIdx.y;
  const int b = bh >> 4, h = bh & 15;
  const int q0 = (15 - blockIdx.x) * 128;    // heavy blocks first
  const int qw0 = q0 + w * 32;
  const int q = qw0 + c31;                   // this lane's q row

  bf16x8 qreg[8];
  {
    const u16* qp = Qb + ((size_t)(b * 2048 + q)) * 2048 + h * 128 + hi * 8;
#pragma unroll
    for (int ks = 0; ks < 8; ks++) qreg[ks] = *(const bf16x8*)(qp + ks * 16);
  }

  const u16* ksrc[4];
  const u16* vsrc[4];
  int xoff[4];
#pragma unroll
  for (int c = 0; c < 4; c++) {
    int X = c * 4096 + tid * 16;
    int row = X >> 8, phys = X & 255;
    int lg = phys ^ ((row & 15) << 4);
    xoff[c] = X;
    ksrc[c] = Kb + (size_t)(b * 2048 + row) * 2048 + h * 128 + (lg >> 1);
    int vd = row + ((lg >> 7) << 6);
    int kvb = lg & 127;
    vsrc[c] = Vt + ((size_t)(b * 16 + h) * 128 + vd) * 2048 + (kvb >> 1);
  }

  f32x16 accO[4] = {};
  float m_run = -__builtin_inff(), l_run = 0.f;

  const int ntiles = (q0 >> 6) + 2;

#pragma unroll
  for (int c = 0; c < 4; c++) {
    GLD16(ksrc[c], (char*)Ks + xoff[c]);
    GLD16(vsrc[c], (char*)Vs + xoff[c]);
    ksrc[c] += (size_t)64 * 2048;
    vsrc[c] += 64;
  }

  for (int it = 0; it < ntiles; it++) {
    const int kv0 = it << 6;
    const int buf = it & 1;
    __syncthreads();
    if (it + 1 < ntiles) {
      const int nb = buf ^ 1;
#pragma unroll
      for (int c = 0; c < 4; c++) {
        GLD16(ksrc[c], (char*)Ks + nb * 16384 + xoff[c]);
        GLD16(vsrc[c], (char*)Vs + nb * 16384 + xoff[c]);
        ksrc[c] += (size_t)64 * 2048;
        vsrc[c] += 64;
      }
    }
    if (kv0 > qw0 + 31) continue;

    // ---- S^T[64kv x 32q] = K * Q^T
    f32x16 sT[2] = {};
    {
      const char* kb = (const char*)Ks + buf * 16384;
#pragma unroll
      for (int kvt = 0; kvt < 2; kvt++) {
        int krow = kvt * 32 + c31;
        const char* kr = kb + krow * 256;
        int swz = (krow & 15) << 4;
#pragma unroll
        for (int ks = 0; ks < 8; ks++) {
          bf16x8 kf = *(const bf16x8*)(kr + ((ks * 32 + hi * 16) ^ swz));
          sT[kvt] = __builtin_amdgcn_mfma_f32_32x32x16_bf16(kf, qreg[ks], sT[kvt], 0, 0, 0);
        }
      }
    }

    if (kv0 + 63 > qw0) {
#pragma unroll
      for (int kvt = 0; kvt < 2; kvt++)
#pragma unroll
        for (int r = 0; r < 16; r++) {
          int kv = kv0 + kvt * 32 + (r & 3) + 8 * (r >> 2) + 4 * hi;
          if (kv > q) sT[kvt][r] = -__builtin_inff();
        }
    }

    float tm[16];
#pragma unroll
    for (int r = 0; r < 16; r++) tm[r] = fmaxf(sT[0][r], sT[1][r]);
#pragma unroll
    for (int st = 8; st > 0; st >>= 1)
#pragma unroll
      for (int r = 0; r < st; r++) tm[r] = fmaxf(tm[r], tm[r + st]);
    float pmax = tm[0];
    pmax = fmaxf(pmax, __shfl_xor(pmax, 32));

    if (!__all(pmax - m_run <= 8.0f)) {
      float mnew = fmaxf(m_run, pmax);
      float alpha = exp2f(m_run - mnew);
      m_run = mnew;
      l_run *= alpha;
#pragma unroll
      for (int r = 0; r < 16; r++) {
        float ar = __shfl(alpha, (r & 3) + 8 * (r >> 2) + 4 * hi);
#pragma unroll
        for (int dt = 0; dt < 4; dt++) accO[dt][r] *= ar;
      }
    }

    float a0 = 0.f, a1 = 0.f, a2 = 0.f, a3 = 0.f;
#pragma unroll
    for (int kvt = 0; kvt < 2; kvt++)
#pragma unroll
      for (int r = 0; r < 16; r++) {
        float p = exp2f(sT[kvt][r] - m_run);
        sT[kvt][r] = p;
        if ((r & 3) == 0) a0 += p; else if ((r & 3) == 1) a1 += p;
        else if ((r & 3) == 2) a2 += p; else a3 += p;
      }
    float rs = (a0 + a1) + (a2 + a3);
    rs += __shfl_xor(rs, 32);
    l_run += rs;

    u32x4 pa[4];
#pragma unroll
    for (int kvt = 0; kvt < 2; kvt++)
#pragma unroll
      for (int hf = 0; hf < 2; hf++) {
        u32 wA0 = cvtpk(sT[kvt][hf * 8 + 0], sT[kvt][hf * 8 + 1]);
        u32 wA1 = cvtpk(sT[kvt][hf * 8 + 4], sT[kvt][hf * 8 + 5]);
        u32 wB0 = cvtpk(sT[kvt][hf * 8 + 2], sT[kvt][hf * 8 + 3]);
        u32 wB1 = cvtpk(sT[kvt][hf * 8 + 6], sT[kvt][hf * 8 + 7]);
        plswap(wA0, wA1);
        plswap(wB0, wB1);
        pa[kvt * 2 + hf] = (u32x4){wA0, wB0, wA1, wB1};
      }

    {
      const char* vb = (const char*)Vs + buf * 16384;
#pragma unroll
      for (int dt = 0; dt < 4; dt++) {
        int vrow = (dt & 1) * 32 + c31;
        const char* vr = vb + vrow * 256;
        int swz = (vrow & 15) << 4;
        int hsel = (dt >> 1) * 128;
#pragma unroll
        for (int ks = 0; ks < 4; ks++) {
          bf16x8 vf = *(const bf16x8*)(vr + ((hsel + ks * 32 + hi * 16) ^ swz));
          bf16x8 paf = __builtin_bit_cast(bf16x8, pa[ks]);
          accO[dt] = __builtin_amdgcn_mfma_f32_32x32x16_bf16(paf, vf, accO[dt], 0, 0, 0);
        }
      }
    }
  }

  float linv = 1.0f / l_run;
#pragma unroll
  for (int r = 0; r < 16; r++) {
    int crow = (r & 3) + 8 * (r >> 2) + 4 * hi;
    float lr = __shfl(linv, crow);
    int qq = qw0 + crow;
    u16* op = AO + (size_t)(b * 2048 + qq) * 2048 + h * 128 + c31;
#pragma unroll
    for (int dt = 0; dt < 4; dt++) op[dt * 32] = f2bf(accO[dt][r] * lr);
  }
}

extern "C" void kernel_launch(void* const* d_in, const int* in_sizes, int n_in,
                              void* d_out, int out_size, void* d_ws, size_t ws_size,
                              hipStream_t stream) {
  const float* x    = (const float*)d_in[0];
  const float* cosT = (const float*)d_in[1];
  const float* sinT = (const float*)d_in[2];
  const float* Wq   = (const float*)d_in[3];
  const float* bq   = (const float*)d_in[4];
  const float* Wk   = (const float*)d_in[5];
  const float* bk   = (const float*)d_in[6];
  const float* Wv   = (const float*)d_in[7];
  const float* bv   = (const float*)d_in[8];
  const float* Wo   = (const float*)d_in[9];
  const float* bo   = (const float*)d_in[10];

  float* out   = (float*)d_out;
  float* k_new = out + (size_t)16777216;   // B*T*C
  float* v_new = out + (size_t)33554432;

  char* ws = (char*)d_ws;
  u16* xb  = (u16*)(ws);                   // 33.5MB  (reused as AO later)
  u16* Wqb = (u16*)(ws + 33554432);        // 8.4MB each
  u16* Wkb = (u16*)(ws + 41943040);
  u16* Wvb = (u16*)(ws + 50331648);
  u16* Wob = (u16*)(ws + 58720256);
  u16* Qb  = (u16*)(ws + 67108864);        // 33.5MB
  u16* Kb  = (u16*)(ws + 100663296);       // 33.5MB
  u16* Vt  = (u16*)(ws + 134217728);       // 33.5MB  (end: 167772160)
  u16* AO  = xb;

  // fp32 -> bf16 staging
  cvt_bf16<<<16384, 256, 0, stream>>>(x, xb, 4194304);
  cvt_bf16<<<4096, 256, 0, stream>>>(Wq, Wqb, 1048576);
  cvt_bf16<<<4096, 256, 0, stream>>>(Wk, Wkb, 1048576);
  cvt_bf16<<<4096, 256, 0, stream>>>(Wv, Wvb, 1048576);
  cvt_bf16<<<4096, 256, 0, stream>>>(Wo, Wob, 1048576);

  // projections (256x256 tile, 512 threads)
  dim3 gg(8, 32);
  gemm_bt<<<gg, 512, 0, stream>>>(xb, Wqb, bq, nullptr, Qb, nullptr);
  gemm_bt<<<gg, 512, 0, stream>>>(xb, Wkb, bk, k_new, Kb, nullptr);
  gemm_bt<<<gg, 512, 0, stream>>>(xb, Wvb, bv, v_new, nullptr, Vt);

  // RoPE: Q gets scale log2(e)/sqrt(128) folded in; K plain
  const float sc2 = 1.44269504088896f * 0.08838834764831845f;
  rope_ip<<<8192, 256, 0, stream>>>(Qb, cosT, sinT, sc2);
  rope_ip<<<8192, 256, 0, stream>>>(Kb, cosT, sinT, 1.0f);

  // causal flash attention -> AO (bf16 [B,T,C])
  attn_fwd<<<dim3(16, 64), 256, 0, stream>>>(Qb, Kb, Vt, AO);

  // output projection
  gemm_bt<<<gg, 512, 0, stream>>>(AO, Wob, bo, out, nullptr, nullptr);
}

// Round 8
// 538.099 us; speedup vs baseline: 1.7239x; 1.0711x over previous
//
#include <hip/hip_runtime.h>

typedef unsigned short u16;
typedef unsigned int u32;

typedef __attribute__((ext_vector_type(8))) short bf16x8;
typedef __attribute__((ext_vector_type(4))) float f32x4;
typedef __attribute__((ext_vector_type(16))) float f32x16;
typedef __attribute__((ext_vector_type(4))) u32 u32x4;

__device__ __forceinline__ u16 f2bf(float f) {
  u32 u = __builtin_bit_cast(u32, f);
  u32 r = (u + 0x7fffu + ((u >> 16) & 1u)) >> 16;
  return (u16)r;
}
__device__ __forceinline__ float bf2f(u16 h) {
  return __builtin_bit_cast(float, (u32)h << 16);
}
__device__ __forceinline__ u32 cvtpk(float lo, float hi) {
  u32 d;
  asm("v_cvt_pk_bf16_f32 %0, %1, %2" : "=v"(d) : "v"(lo), "v"(hi));
  return d;
}
// v_permlane32_swap_b32: a.hi <-> b.lo.  After: a={a.lo, b.lo}, b={a.hi, b.hi}
__device__ __forceinline__ void plswap(u32& a, u32& b) {
  asm("v_permlane32_swap_b32 %0, %1" : "+v"(a), "+v"(b));
}

#define GLD16(g, l)                                       \
  __builtin_amdgcn_global_load_lds(                       \
      (__attribute__((address_space(1))) void*)(g),       \
      (__attribute__((address_space(3))) void*)(l), 16, 0, 0)

#define WAITV8() asm volatile("s_waitcnt vmcnt(8)" ::: "memory")
#define WAITV0() asm volatile("s_waitcnt vmcnt(0)" ::: "memory")
#define BARF()                               \
  {                                          \
    asm volatile("" ::: "memory");           \
    __builtin_amdgcn_s_barrier();            \
    asm volatile("" ::: "memory");           \
  }

// ---------------- fp32 -> bf16 convert ----------------
__global__ __launch_bounds__(256) void cvt_bf16(const float* __restrict__ src,
                                                u16* __restrict__ dst, int n4) {
  int i = blockIdx.x * 256 + threadIdx.x;
  if (i >= n4) return;
  float4 v = ((const float4*)src)[i];
  ushort4 o;
  o.x = f2bf(v.x); o.y = f2bf(v.y); o.z = f2bf(v.z); o.w = f2bf(v.w);
  ((ushort4*)dst)[i] = o;
}

// ---------------- 4 weight matrices fp32 -> bf16 in one launch ----------------
// each weight: 2048x2048 f32 = 1048576 float4 -> 4096 blocks of 256 threads.
// grid = 16384 blocks total (j = block >> 12).  [R6/R7 bug: >>10 converted 1/4]
__global__ __launch_bounds__(256) void cvt_w4(const float* __restrict__ s0,
                                              const float* __restrict__ s1,
                                              const float* __restrict__ s2,
                                              const float* __restrict__ s3,
                                              u16* __restrict__ d0,
                                              u16* __restrict__ d1,
                                              u16* __restrict__ d2,
                                              u16* __restrict__ d3) {
  int j = blockIdx.x >> 12;
  int i = (blockIdx.x & 4095) * 256 + threadIdx.x;
  const float* src = (j == 0) ? s0 : (j == 1) ? s1 : (j == 2) ? s2 : s3;
  u16* dst = (j == 0) ? d0 : (j == 1) ? d1 : (j == 2) ? d2 : d3;
  float4 v = ((const float4*)src)[i];
  ushort4 o;
  o.x = f2bf(v.x); o.y = f2bf(v.y); o.z = f2bf(v.z); o.w = f2bf(v.w);
  ((ushort4*)dst)[i] = o;
}

// ---------------- RoPE in place on bf16 Q and K together ----------------
__global__ __launch_bounds__(256) void rope2(u16* __restrict__ qb,
                                             u16* __restrict__ kb,
                                             const float* __restrict__ cosT,
                                             const float* __restrict__ sinT,
                                             float scaleQ) {
  int i = blockIdx.x * 256 + threadIdx.x;  // < B*T*256 = 2097152
  int c4 = (i & 255) << 2;                 // 0..1020
  size_t bt = (size_t)(i >> 8);
  int t = (int)(bt & 2047);
  float4 c1 = *(const float4*)&cosT[(size_t)t * 2048 + c4];
  float4 s1 = *(const float4*)&sinT[(size_t)t * 2048 + c4];
  float4 c2 = *(const float4*)&cosT[(size_t)t * 2048 + c4 + 1024];
  float4 s2 = *(const float4*)&sinT[(size_t)t * 2048 + c4 + 1024];
#pragma unroll
  for (int which = 0; which < 2; which++) {
    u16* buf = which ? kb : qb;
    float scale = which ? 1.0f : scaleQ;
    u16* p1 = buf + bt * 2048 + c4;
    u16* p2 = p1 + 1024;
    ushort4 x1 = *(const ushort4*)p1;
    ushort4 x2 = *(const ushort4*)p2;
    float a0 = bf2f(x1.x), a1 = bf2f(x1.y), a2 = bf2f(x1.z), a3 = bf2f(x1.w);
    float b0 = bf2f(x2.x), b1 = bf2f(x2.y), b2 = bf2f(x2.z), b3 = bf2f(x2.w);
    ushort4 o1, o2;
    o1.x = f2bf((a0 * c1.x - b0 * s1.x) * scale);
    o1.y = f2bf((a1 * c1.y - b1 * s1.y) * scale);
    o1.z = f2bf((a2 * c1.z - b2 * s1.z) * scale);
    o1.w = f2bf((a3 * c1.w - b3 * s1.w) * scale);
    o2.x = f2bf((b0 * c2.x + a0 * s2.x) * scale);
    o2.y = f2bf((b1 * c2.y + a1 * s2.y) * scale);
    o2.z = f2bf((b2 * c2.z + a2 * s2.z) * scale);
    o2.w = f2bf((b3 * c2.w + a3 * s2.w) * scale);
    *(ushort4*)p1 = o1;
    *(ushort4*)p2 = o2;
  }
}

// ---------------- bf16 GEMM: D[m][n] = sum_k A[m][k]*W[n][k] + bias[n] ----------
// 256x256 tile, BK=64, 8 waves (2M x 4N), per-wave 128x64. LDS 128KB double-buffered.
// Counted vmcnt(8). XCD-aware block swizzle (grid must be 8x32 = 256 blocks).
__global__ __launch_bounds__(512, 2) void gemm_bt(const u16* __restrict__ A,
                                                  const u16* __restrict__ Wm,
                                                  const float* __restrict__ bias,
                                                  float* __restrict__ outF,
                                                  u16* __restrict__ outB,
                                                  u16* __restrict__ outT) {
  // regions (bytes): A slot0 @0, A slot1 @32768, B slot0 @65536, B slot1 @98304
  __shared__ __attribute__((aligned(16))) char L[131072];
  const int tid = threadIdx.x;
  const int lane = tid & 63;
  const int w = tid >> 6;        // 0..7
  const int wr = w >> 2;         // 0..1 : M half
  const int wcn = w & 3;         // 0..3 : N quarter
  // T1: XCD swizzle. lin 0..255 round-robins over 8 XCDs; transpose so each XCD
  // owns 4 contiguous M-panels (4MB A-panel reuse in its private L2).
  const int lin = blockIdx.y * 8 + blockIdx.x;
  const int swz = ((lin & 7) << 5) | (lin >> 3);
  const int m0 = (swz >> 3) * 256, n0 = (swz & 7) * 256;
  const int r15 = lane & 15, rg = lane >> 4;
  const int sw = (r15 & 7) << 4;

  const int trow = tid >> 3;
  const int tlog = ((tid & 7) << 4) ^ ((trow & 7) << 4);
  const u16* pA = A + (size_t)(m0 + trow) * 2048 + (tlog >> 1);
  const u16* pB = Wm + (size_t)(n0 + trow) * 2048 + (tlog >> 1);
  char* dA = L + tid * 16;
  char* dB = L + 65536 + tid * 16;

#define STAGE(dst, src, koff)                                   \
  {                                                             \
    _Pragma("unroll")                                           \
    for (int c = 0; c < 4; c++)                                 \
      GLD16((src) + (size_t)c * 131072 + (koff), (dst) + c * 8192); \
  }

  const char* aBase = L + wr * 16384;
  const char* bBase = L + 65536 + (wcn >> 1) * 16384 + (wcn & 1) * 8192;

  f32x4 acc[8][4] = {};
  bf16x8 ar[4][2], br[2][2][2];

  auto LD_A = [&](int mq, int soff) {
#pragma unroll
    for (int mf = 0; mf < 4; mf++)
#pragma unroll
      for (int ks = 0; ks < 2; ks++) {
        int row = mq * 64 + mf * 16 + r15;
        ar[mf][ks] = *(const bf16x8*)(aBase + soff + row * 128 +
                                      ((ks * 64 + rg * 16) ^ sw));
      }
  };
  auto LD_B = [&](int nq, int soff) {
#pragma unroll
    for (int nf = 0; nf < 2; nf++)
#pragma unroll
      for (int ks = 0; ks < 2; ks++) {
        int row = nq * 32 + nf * 16 + r15;
        br[nq][nf][ks] = *(const bf16x8*)(bBase + soff + row * 128 +
                                          ((ks * 64 + rg * 16) ^ sw));
      }
  };
  auto QUAD = [&](int mq, int nq) {
#pragma unroll
    for (int mf = 0; mf < 4; mf++)
#pragma unroll
      for (int nf = 0; nf < 2; nf++)
#pragma unroll
        for (int ks = 0; ks < 2; ks++)
          acc[mq * 4 + mf][nq * 2 + nf] = __builtin_amdgcn_mfma_f32_16x16x32_bf16(
              ar[mf][ks], br[nq][nf][ks], acc[mq * 4 + mf][nq * 2 + nf], 0, 0, 0);
  };
  auto COMPUTE = [&](int soff) {
    LD_A(0, soff);
    LD_B(0, soff);
    LD_B(1, soff);
    __builtin_amdgcn_s_setprio(1);
    QUAD(0, 0);
    QUAD(0, 1);
    __builtin_amdgcn_s_setprio(0);
    LD_A(1, soff);
    __builtin_amdgcn_s_setprio(1);
    QUAD(1, 1);
    QUAD(1, 0);
    __builtin_amdgcn_s_setprio(0);
  };

  STAGE(dA, pA, 0);
  STAGE(dB, pB, 0);
  asm volatile("" ::: "memory");
  STAGE(dA + 32768, pA, 64);
  STAGE(dB + 32768, pB, 64);
  WAITV8();
  BARF();

  for (int it = 0; it < 16; it++) {
    COMPUTE(0);
    BARF();
    if (it < 15) {
      STAGE(dA, pA, (2 * it + 2) * 64);
      STAGE(dB, pB, (2 * it + 2) * 64);
      WAITV8();
    } else {
      WAITV0();
    }
    BARF();
    COMPUTE(32768);
    if (it < 15) {
      BARF();
      STAGE(dA + 32768, pA, (2 * it + 3) * 64);
      STAGE(dB + 32768, pB, (2 * it + 3) * 64);
      WAITV8();
      BARF();
    }
  }

#pragma unroll
  for (int am = 0; am < 8; am++)
#pragma unroll
    for (int bn = 0; bn < 4; bn++) {
      int n = n0 + wcn * 64 + bn * 16 + r15;
      float bs = bias[n];
#pragma unroll
      for (int i = 0; i < 4; i++) {
        int m = m0 + wr * 128 + am * 16 + rg * 4 + i;
        float v = acc[am][bn][i] + bs;
        if (outF) outF[(size_t)m * 2048 + n] = v;
        if (outB) outB[(size_t)m * 2048 + n] = f2bf(v);
        if (outT) {
          int b_ = m >> 11, t_ = m & 2047, h_ = n >> 7, d_ = n & 127;
          outT[(((size_t)(b_ * 16 + h_) * 128 + d_) << 11) + t_] = f2bf(v);
        }
      }
    }
#undef STAGE
}

// ---------------- causal flash attention, 32x32 swapped-QK structure ----------
// (round-5 proven version, verbatim)
// grid (T/128, B*H), 256 threads = 4 waves, each wave owns 32 q rows. KVBLK=64.
__global__ __launch_bounds__(256, 2) void attn_fwd(const u16* __restrict__ Qb,
                                                   const u16* __restrict__ Kb,
                                                   const u16* __restrict__ Vt,
                                                   u16* __restrict__ AO) {
  __shared__ __attribute__((aligned(16))) u16 Ks[2][64 * 128];
  __shared__ __attribute__((aligned(16))) u16 Vs[2][64 * 128];
  const int tid = threadIdx.x;
  const int lane = tid & 63;
  const int w = tid >> 6;                    // 0..3
  const int c31 = lane & 31, hi = lane >> 5;
  const int bh = blockIdx.y;
  const int b = bh >> 4, h = bh & 15;
  const int q0 = (15 - blockIdx.x) * 128;    // heavy blocks first
  const int qw0 = q0 + w * 32;
  const int q = qw0 + c31;                   // this lane's q row

  bf16x8 qreg[8];
  {
    const u16* qp = Qb + ((size_t)(b * 2048 + q)) * 2048 + h * 128 + hi * 8;
#pragma unroll
    for (int ks = 0; ks < 8; ks++) qreg[ks] = *(const bf16x8*)(qp + ks * 16);
  }

  const u16* ksrc[4];
  const u16* vsrc[4];
  int xoff[4];
#pragma unroll
  for (int c = 0; c < 4; c++) {
    int X = c * 4096 + tid * 16;
    int row = X >> 8, phys = X & 255;
    int lg = phys ^ ((row & 15) << 4);
    xoff[c] = X;
    ksrc[c] = Kb + (size_t)(b * 2048 + row) * 2048 + h * 128 + (lg >> 1);
    int vd = row + ((lg >> 7) << 6);
    int kvb = lg & 127;
    vsrc[c] = Vt + ((size_t)(b * 16 + h) * 128 + vd) * 2048 + (kvb >> 1);
  }

  f32x16 accO[4] = {};
  float m_run = -__builtin_inff(), l_run = 0.f;

  const int ntiles = (q0 >> 6) + 2;

#pragma unroll
  for (int c = 0; c < 4; c++) {
    GLD16(ksrc[c], (char*)Ks + xoff[c]);
    GLD16(vsrc[c], (char*)Vs + xoff[c]);
    ksrc[c] += (size_t)64 * 2048;
    vsrc[c] += 64;
  }

  for (int it = 0; it < ntiles; it++) {
    const int kv0 = it << 6;
    const int buf = it & 1;
    __syncthreads();
    if (it + 1 < ntiles) {
      const int nb = buf ^ 1;
#pragma unroll
      for (int c = 0; c < 4; c++) {
        GLD16(ksrc[c], (char*)Ks + nb * 16384 + xoff[c]);
        GLD16(vsrc[c], (char*)Vs + nb * 16384 + xoff[c]);
        ksrc[c] += (size_t)64 * 2048;
        vsrc[c] += 64;
      }
    }
    if (kv0 > qw0 + 31) continue;

    // ---- S^T[64kv x 32q] = K * Q^T
    f32x16 sT[2] = {};
    {
      const char* kb = (const char*)Ks + buf * 16384;
#pragma unroll
      for (int kvt = 0; kvt < 2; kvt++) {
        int krow = kvt * 32 + c31;
        const char* kr = kb + krow * 256;
        int swz = (krow & 15) << 4;
#pragma unroll
        for (int ks = 0; ks < 8; ks++) {
          bf16x8 kf = *(const bf16x8*)(kr + ((ks * 32 + hi * 16) ^ swz));
          sT[kvt] = __builtin_amdgcn_mfma_f32_32x32x16_bf16(kf, qreg[ks], sT[kvt], 0, 0, 0);
        }
      }
    }

    if (kv0 + 63 > qw0) {
#pragma unroll
      for (int kvt = 0; kvt < 2; kvt++)
#pragma unroll
        for (int r = 0; r < 16; r++) {
          int kv = kv0 + kvt * 32 + (r & 3) + 8 * (r >> 2) + 4 * hi;
          if (kv > q) sT[kvt][r] = -__builtin_inff();
        }
    }

    float tm[16];
#pragma unroll
    for (int r = 0; r < 16; r++) tm[r] = fmaxf(sT[0][r], sT[1][r]);
#pragma unroll
    for (int st = 8; st > 0; st >>= 1)
#pragma unroll
      for (int r = 0; r < st; r++) tm[r] = fmaxf(tm[r], tm[r + st]);
    float pmax = tm[0];
    pmax = fmaxf(pmax, __shfl_xor(pmax, 32));

    if (!__all(pmax - m_run <= 8.0f)) {  // defer-max (T13)
      float mnew = fmaxf(m_run, pmax);
      float alpha = exp2f(m_run - mnew);
      m_run = mnew;
      l_run *= alpha;
#pragma unroll
      for (int r = 0; r < 16; r++) {
        float ar = __shfl(alpha, (r & 3) + 8 * (r >> 2) + 4 * hi);
#pragma unroll
        for (int dt = 0; dt < 4; dt++) accO[dt][r] *= ar;
      }
    }

    float a0 = 0.f, a1 = 0.f, a2 = 0.f, a3 = 0.f;
#pragma unroll
    for (int kvt = 0; kvt < 2; kvt++)
#pragma unroll
      for (int r = 0; r < 16; r++) {
        float p = exp2f(sT[kvt][r] - m_run);
        sT[kvt][r] = p;
        if ((r & 3) == 0) a0 += p; else if ((r & 3) == 1) a1 += p;
        else if ((r & 3) == 2) a2 += p; else a3 += p;
      }
    float rs = (a0 + a1) + (a2 + a3);
    rs += __shfl_xor(rs, 32);
    l_run += rs;

    u32x4 pa[4];
#pragma unroll
    for (int kvt = 0; kvt < 2; kvt++)
#pragma unroll
      for (int hf = 0; hf < 2; hf++) {
        u32 wA0 = cvtpk(sT[kvt][hf * 8 + 0], sT[kvt][hf * 8 + 1]);
        u32 wA1 = cvtpk(sT[kvt][hf * 8 + 4], sT[kvt][hf * 8 + 5]);
        u32 wB0 = cvtpk(sT[kvt][hf * 8 + 2], sT[kvt][hf * 8 + 3]);
        u32 wB1 = cvtpk(sT[kvt][hf * 8 + 6], sT[kvt][hf * 8 + 7]);
        plswap(wA0, wA1);
        plswap(wB0, wB1);
        pa[kvt * 2 + hf] = (u32x4){wA0, wB0, wA1, wB1};
      }

    {
      const char* vb = (const char*)Vs + buf * 16384;
#pragma unroll
      for (int dt = 0; dt < 4; dt++) {
        int vrow = (dt & 1) * 32 + c31;
        const char* vr = vb + vrow * 256;
        int swz = (vrow & 15) << 4;
        int hsel = (dt >> 1) * 128;
#pragma unroll
        for (int ks = 0; ks < 4; ks++) {
          bf16x8 vf = *(const bf16x8*)(vr + ((hsel + ks * 32 + hi * 16) ^ swz));
          bf16x8 paf = __builtin_bit_cast(bf16x8, pa[ks]);
          accO[dt] = __builtin_amdgcn_mfma_f32_32x32x16_bf16(paf, vf, accO[dt], 0, 0, 0);
        }
      }
    }
  }

  float linv = 1.0f / l_run;
#pragma unroll
  for (int r = 0; r < 16; r++) {
    int crow = (r & 3) + 8 * (r >> 2) + 4 * hi;
    float lr = __shfl(linv, crow);
    int qq = qw0 + crow;
    u16* op = AO + (size_t)(b * 2048 + qq) * 2048 + h * 128 + c31;
#pragma unroll
    for (int dt = 0; dt < 4; dt++) op[dt * 32] = f2bf(accO[dt][r] * lr);
  }
}

extern "C" void kernel_launch(void* const* d_in, const int* in_sizes, int n_in,
                              void* d_out, int out_size, void* d_ws, size_t ws_size,
                              hipStream_t stream) {
  const float* x    = (const float*)d_in[0];
  const float* cosT = (const float*)d_in[1];
  const float* sinT = (const float*)d_in[2];
  const float* Wq   = (const float*)d_in[3];
  const float* bq   = (const float*)d_in[4];
  const float* Wk   = (const float*)d_in[5];
  const float* bk   = (const float*)d_in[6];
  const float* Wv   = (const float*)d_in[7];
  const float* bv   = (const float*)d_in[8];
  const float* Wo   = (const float*)d_in[9];
  const float* bo   = (const float*)d_in[10];

  float* out   = (float*)d_out;
  float* k_new = out + (size_t)16777216;   // B*T*C
  float* v_new = out + (size_t)33554432;

  char* ws = (char*)d_ws;
  u16* xb  = (u16*)(ws);                   // 33.5MB  (reused as AO later)
  u16* Wqb = (u16*)(ws + 33554432);        // 8.4MB each
  u16* Wkb = (u16*)(ws + 41943040);
  u16* Wvb = (u16*)(ws + 50331648);
  u16* Wob = (u16*)(ws + 58720256);
  u16* Qb  = (u16*)(ws + 67108864);        // 33.5MB
  u16* Kb  = (u16*)(ws + 100663296);       // 33.5MB
  u16* Vt  = (u16*)(ws + 134217728);       // 33.5MB  (end: 167772160)
  u16* AO  = xb;

  // fp32 -> bf16 staging
  cvt_bf16<<<16384, 256, 0, stream>>>(x, xb, 4194304);
  cvt_w4<<<16384, 256, 0, stream>>>(Wq, Wk, Wv, Wo, Wqb, Wkb, Wvb, Wob);

  // projections (256x256 tile, 512 threads)
  dim3 gg(8, 32);
  gemm_bt<<<gg, 512, 0, stream>>>(xb, Wqb, bq, nullptr, Qb, nullptr);
  gemm_bt<<<gg, 512, 0, stream>>>(xb, Wkb, bk, k_new, Kb, nullptr);
  gemm_bt<<<gg, 512, 0, stream>>>(xb, Wvb, bv, v_new, nullptr, Vt);

  // RoPE on Q (+scale fold) and K in one pass
  const float sc2 = 1.44269504088896f * 0.08838834764831845f;
  rope2<<<8192, 256, 0, stream>>>(Qb, Kb, cosT, sinT, sc2);

  // causal flash attention -> AO (bf16 [B,T,C])
  attn_fwd<<<dim3(16, 64), 256, 0, stream>>>(Qb, Kb, Vt, AO);

  // output projection
  gemm_bt<<<gg, 512, 0, stream>>>(AO, Wob, bo, out, nullptr, nullptr);
}